// Round 1
// baseline (947.632 us; speedup 1.0000x reference)
//
#include <hip/hip_runtime.h>
#include <hip/hip_bf16.h>
#include <cstdint>

#define DIN 1024
#define DH  2048
#define DR  256
#define SEQ 4096
#define NB  4
#define MTOK (NB*SEQ)   // 16384

typedef __attribute__((ext_vector_type(8))) short bf16x8;
typedef __attribute__((ext_vector_type(4))) float f32x4;

__device__ __forceinline__ unsigned short f2bf(float f) {
  union { float f; unsigned u; } v; v.f = f;
  unsigned r = v.u + 0x7fffu + ((v.u >> 16) & 1u);
  return (unsigned short)(r >> 16);
}

__device__ __forceinline__ float sigmoidf_(float x) {
  return 1.0f / (1.0f + __expf(-x));
}

// ---- cast f32 (strided rows) -> bf16 (packed rows) ----
__global__ void cast_strided_kernel(const float* __restrict__ src,
                                    unsigned short* __restrict__ dst,
                                    int rows, int cols, int src_ld) {
  int cols4 = cols >> 2;
  int total = rows * cols4;
  for (int i = blockIdx.x * blockDim.x + threadIdx.x; i < total;
       i += gridDim.x * blockDim.x) {
    int r  = i / cols4;
    int c4 = i - r * cols4;
    const float4 v = *reinterpret_cast<const float4*>(src + (size_t)r * src_ld + c4 * 4);
    ushort4 o;
    o.x = f2bf(v.x); o.y = f2bf(v.y); o.z = f2bf(v.z); o.w = f2bf(v.w);
    *reinterpret_cast<ushort4*>(dst + (size_t)r * cols + c4 * 4) = o;
  }
}

// ---- hidden-part projections: hd_gate[b][ch] = W_gate[ch,1024:] . hidden[b]
//                               hd_delta[b][r] = W_delta[r,1024:] . hidden[b]
__global__ void hd_kernel(const float* __restrict__ Wg, const float* __restrict__ Wd,
                          const float* __restrict__ hidden,
                          float* __restrict__ hd_gate, float* __restrict__ hd_delta) {
  int wid  = (blockIdx.x * blockDim.x + threadIdx.x) >> 6;
  int lane = threadIdx.x & 63;
  if (wid >= DH + DR) return;
  const float* wrow;
  int ch; bool isGate;
  if (wid < DH) { isGate = true;  ch = wid;      wrow = Wg + (size_t)ch * (DIN + DH) + DIN; }
  else          { isGate = false; ch = wid - DH; wrow = Wd + (size_t)ch * (DIN + DH) + DIN; }
  float acc[NB] = {0.f, 0.f, 0.f, 0.f};
  for (int k = lane; k < DH; k += 64) {
    float w = wrow[k];
    #pragma unroll
    for (int b = 0; b < NB; b++) acc[b] += w * hidden[b * DH + k];
  }
  #pragma unroll
  for (int b = 0; b < NB; b++) {
    float v = acc[b];
    #pragma unroll
    for (int off = 32; off; off >>= 1) v += __shfl_down(v, off);
    if (lane == 0) {
      if (isGate) hd_gate[b * DH + ch] = v;
      else        hd_delta[b * DR + ch] = v;
    }
  }
}

// ---- LDS staging with XOR swizzle: tile [rows][64] bf16, row = 128B = 8 chunks of 16B
__device__ __forceinline__ void stage_tile(const unsigned short* __restrict__ src,
                                           int src_ld, unsigned short* lds,
                                           int rows, int tid) {
  int nchunks = rows * 8;
  for (int id = tid; id < nchunks; id += 256) {
    int r = id >> 3, c = id & 7;
    uint4 v = *reinterpret_cast<const uint4*>(src + (size_t)r * src_ld + c * 8);
    int csw = c ^ (r & 7);
    *reinterpret_cast<uint4*>(lds + r * 64 + csw * 8) = v;
  }
}

__device__ __forceinline__ bf16x8 read_frag(const unsigned short* lds, int row,
                                            int kk, int lane) {
  int c = (kk * 4 + (lane >> 4)) ^ (row & 7);
  return *reinterpret_cast<const bf16x8*>(lds + row * 64 + c * 8);
}

// ---- GEMM: P = silu(Xb @ Wd_x^T + hd_delta)  -> bf16 [MTOK][DR]
__global__ __launch_bounds__(256, 2) void gemm_P(
    const unsigned short* __restrict__ Xb, const unsigned short* __restrict__ Wdb,
    const float* __restrict__ hd_delta, unsigned short* __restrict__ P) {
  __shared__ __align__(16) unsigned short As[128 * 64];
  __shared__ __align__(16) unsigned short Bs[64 * 64];
  int tid = threadIdx.x, lane = tid & 63, wid = tid >> 6;
  int wm = wid >> 1, wn = wid & 1;
  int bm0 = blockIdx.x * 128;
  int bn0 = blockIdx.y * 64;
  f32x4 acc[4][2];
  #pragma unroll
  for (int m = 0; m < 4; m++)
    #pragma unroll
    for (int n = 0; n < 2; n++) acc[m][n] = (f32x4){0.f, 0.f, 0.f, 0.f};

  for (int k0 = 0; k0 < DIN; k0 += 64) {
    stage_tile(Xb + (size_t)bm0 * DIN + k0, DIN, As, 128, tid);
    stage_tile(Wdb + (size_t)bn0 * DIN + k0, DIN, Bs, 64, tid);
    __syncthreads();
    #pragma unroll
    for (int kk = 0; kk < 2; kk++) {
      bf16x8 af[4], bf[2];
      #pragma unroll
      for (int m = 0; m < 4; m++) af[m] = read_frag(As, wm * 64 + m * 16 + (lane & 15), kk, lane);
      #pragma unroll
      for (int n = 0; n < 2; n++) bf[n] = read_frag(Bs, wn * 32 + n * 16 + (lane & 15), kk, lane);
      #pragma unroll
      for (int m = 0; m < 4; m++)
        #pragma unroll
        for (int n = 0; n < 2; n++)
          acc[m][n] = __builtin_amdgcn_mfma_f32_16x16x32_bf16(af[m], bf[n], acc[m][n], 0, 0, 0);
    }
    __syncthreads();
  }
  int batch = bm0 >> 12;
  #pragma unroll
  for (int n = 0; n < 2; n++) {
    int ch = bn0 + wn * 32 + n * 16 + (lane & 15);
    float hd = hd_delta[batch * DR + ch];
    #pragma unroll
    for (int m = 0; m < 4; m++) {
      #pragma unroll
      for (int r = 0; r < 4; r++) {
        int tok = bm0 + wm * 64 + m * 16 + (lane >> 4) * 4 + r;
        float v = acc[m][n][r] + hd;
        v = v * sigmoidf_(v);   // silu
        P[(size_t)tok * DR + ch] = f2bf(v);
      }
    }
  }
}

// ---- fused GEMM: acc_v = X@Wv^T, acc_g = X@Wg^T (K=1024); acc_d = P@We^T (K=256)
//      a = 1-sigmoid(g'), b = sigmoid(g')*(silu(v')+d')
__global__ __launch_bounds__(256, 2) void gemm_fused(
    const unsigned short* __restrict__ Xb, const unsigned short* __restrict__ Wvb,
    const unsigned short* __restrict__ Wgb, const unsigned short* __restrict__ P,
    const unsigned short* __restrict__ Web,
    const float* __restrict__ b_value, const float* __restrict__ b_gate,
    const float* __restrict__ b_expand, const float* __restrict__ hd_gate,
    float* __restrict__ ws_a, float* __restrict__ out_b) {
  __shared__ __align__(16) unsigned short As[128 * 64];
  __shared__ __align__(16) unsigned short Bv[64 * 64];
  __shared__ __align__(16) unsigned short Bg[64 * 64];
  int tid = threadIdx.x, lane = tid & 63, wid = tid >> 6;
  int wm = wid >> 1, wn = wid & 1;
  int bm0 = blockIdx.x * 128;
  int bn0 = blockIdx.y * 64;
  f32x4 acc_v[4][2], acc_g[4][2], acc_d[4][2];
  #pragma unroll
  for (int m = 0; m < 4; m++)
    #pragma unroll
    for (int n = 0; n < 2; n++) {
      acc_v[m][n] = (f32x4){0.f, 0.f, 0.f, 0.f};
      acc_g[m][n] = (f32x4){0.f, 0.f, 0.f, 0.f};
      acc_d[m][n] = (f32x4){0.f, 0.f, 0.f, 0.f};
    }

  // K1: value + gate projections (share the X tile)
  for (int k0 = 0; k0 < DIN; k0 += 64) {
    stage_tile(Xb + (size_t)bm0 * DIN + k0, DIN, As, 128, tid);
    stage_tile(Wvb + (size_t)bn0 * DIN + k0, DIN, Bv, 64, tid);
    stage_tile(Wgb + (size_t)bn0 * DIN + k0, DIN, Bg, 64, tid);
    __syncthreads();
    #pragma unroll
    for (int kk = 0; kk < 2; kk++) {
      bf16x8 af[4], bvf[2], bgf[2];
      #pragma unroll
      for (int m = 0; m < 4; m++) af[m] = read_frag(As, wm * 64 + m * 16 + (lane & 15), kk, lane);
      #pragma unroll
      for (int n = 0; n < 2; n++) {
        bvf[n] = read_frag(Bv, wn * 32 + n * 16 + (lane & 15), kk, lane);
        bgf[n] = read_frag(Bg, wn * 32 + n * 16 + (lane & 15), kk, lane);
      }
      #pragma unroll
      for (int m = 0; m < 4; m++)
        #pragma unroll
        for (int n = 0; n < 2; n++) {
          acc_v[m][n] = __builtin_amdgcn_mfma_f32_16x16x32_bf16(af[m], bvf[n], acc_v[m][n], 0, 0, 0);
          acc_g[m][n] = __builtin_amdgcn_mfma_f32_16x16x32_bf16(af[m], bgf[n], acc_g[m][n], 0, 0, 0);
        }
    }
    __syncthreads();
  }
  // K2: delta expand (P @ We^T), K = 256
  for (int k0 = 0; k0 < DR; k0 += 64) {
    stage_tile(P + (size_t)bm0 * DR + k0, DR, As, 128, tid);
    stage_tile(Web + (size_t)bn0 * DR + k0, DR, Bv, 64, tid);
    __syncthreads();
    #pragma unroll
    for (int kk = 0; kk < 2; kk++) {
      bf16x8 af[4], bef[2];
      #pragma unroll
      for (int m = 0; m < 4; m++) af[m] = read_frag(As, wm * 64 + m * 16 + (lane & 15), kk, lane);
      #pragma unroll
      for (int n = 0; n < 2; n++) bef[n] = read_frag(Bv, wn * 32 + n * 16 + (lane & 15), kk, lane);
      #pragma unroll
      for (int m = 0; m < 4; m++)
        #pragma unroll
        for (int n = 0; n < 2; n++)
          acc_d[m][n] = __builtin_amdgcn_mfma_f32_16x16x32_bf16(af[m], bef[n], acc_d[m][n], 0, 0, 0);
    }
    __syncthreads();
  }
  // epilogue
  int batch = bm0 >> 12;
  #pragma unroll
  for (int n = 0; n < 2; n++) {
    int ch = bn0 + wn * 32 + n * 16 + (lane & 15);
    float bv_ = b_value[ch];
    float bg_ = b_gate[ch] + hd_gate[batch * DH + ch];
    float be_ = b_expand[ch];
    #pragma unroll
    for (int m = 0; m < 4; m++) {
      #pragma unroll
      for (int r = 0; r < 4; r++) {
        int tok = bm0 + wm * 64 + m * 16 + (lane >> 4) * 4 + r;
        float vv = acc_v[m][n][r] + bv_;
        vv = vv * sigmoidf_(vv);                       // silu(value)
        float gg = sigmoidf_(acc_g[m][n][r] + bg_);    // gate
        float dd = acc_d[m][n][r] + be_;               // delta
        size_t idx = (size_t)tok * DH + ch;
        ws_a[idx]  = 1.0f - gg;
        out_b[idx] = gg * (vv + dd);
      }
    }
  }
}

// ---- sequential scan over S, one thread per (batch, channel), in place over out ----
__global__ void scan_kernel(const float* __restrict__ ws_a, float* __restrict__ out,
                            const float* __restrict__ hidden) {
  int id = blockIdx.x * blockDim.x + threadIdx.x;   // 0..8191
  int b = id >> 11;
  int ch = id & (DH - 1);
  float h = hidden[id];
  size_t base = (size_t)b * SEQ * DH + ch;
  #pragma unroll 8
  for (int t = 0; t < SEQ; t++) {
    size_t idx = base + (size_t)t * DH;
    float a  = ws_a[idx];
    float bc = out[idx];
    h = fmaf(a, h, bc);
    out[idx] = h;
  }
  out[(size_t)MTOK * DH + id] = h;
}

extern "C" void kernel_launch(void* const* d_in, const int* in_sizes, int n_in,
                              void* d_out, int out_size, void* d_ws, size_t ws_size,
                              hipStream_t stream) {
  (void)in_sizes; (void)n_in; (void)out_size; (void)ws_size;
  const float* x      = (const float*)d_in[0];
  const float* hidden = (const float*)d_in[1];
  const float* Wd     = (const float*)d_in[2];
  const float* We     = (const float*)d_in[3];
  const float* be     = (const float*)d_in[4];
  const float* Wg     = (const float*)d_in[5];
  const float* bg     = (const float*)d_in[6];
  const float* Wv     = (const float*)d_in[7];
  const float* bv     = (const float*)d_in[8];
  float* out = (float*)d_out;
  char* ws = (char*)d_ws;

  float*          ws_a     = (float*)(ws);                     // 134217728 B
  unsigned short* Xb       = (unsigned short*)(ws + 134217728); // 33554432 B
  unsigned short* Pb       = (unsigned short*)(ws + 167772160); // 8388608 B
  unsigned short* Wvb      = (unsigned short*)(ws + 176160768); // 4194304 B
  unsigned short* Wgb      = (unsigned short*)(ws + 180355072); // 4194304 B
  unsigned short* Wdb      = (unsigned short*)(ws + 184549376); // 524288 B
  unsigned short* Web      = (unsigned short*)(ws + 185073664); // 1048576 B
  float*          hd_gate  = (float*)(ws + 186122240);          // 32768 B
  float*          hd_delta = (float*)(ws + 186155008);          // 4096 B

  // bf16 casts
  cast_strided_kernel<<<2048, 256, 0, stream>>>(x,  Xb,  MTOK, DIN, DIN);
  cast_strided_kernel<<<512,  256, 0, stream>>>(Wv, Wvb, DH,   DIN, DIN);
  cast_strided_kernel<<<512,  256, 0, stream>>>(Wg, Wgb, DH,   DIN, DIN + DH);
  cast_strided_kernel<<<64,   256, 0, stream>>>(Wd, Wdb, DR,   DIN, DIN + DH);
  cast_strided_kernel<<<128,  256, 0, stream>>>(We, Web, DH,   DR,  DR);
  // hidden-part bias projections (f32, faithful to general hidden)
  hd_kernel<<<(DH + DR) / 4, 256, 0, stream>>>(Wg, Wd, hidden, hd_gate, hd_delta);
  // P = silu(delta_latent)
  gemm_P<<<dim3(MTOK / 128, DR / 64), 256, 0, stream>>>(Xb, Wdb, hd_delta, Pb);
  // a -> ws, b -> out (in place for scan)
  gemm_fused<<<dim3(MTOK / 128, DH / 64), 256, 0, stream>>>(
      Xb, Wvb, Wgb, Pb, Web, bv, bg, be, hd_gate, ws_a, out);
  // linear recurrence
  scan_kernel<<<32, 256, 0, stream>>>(ws_a, out, hidden);
}

// Round 5
// 528.999 us; speedup vs baseline: 1.7914x; 1.7914x over previous
//
#include <hip/hip_runtime.h>
#include <hip/hip_bf16.h>
#include <cstdint>

#define DIN 1024
#define DH  2048
#define DR  256
#define SEQ 4096
#define NB  4
#define MTOK (NB*SEQ)   // 16384
#define NCHUNK 64
#define CL (SEQ/NCHUNK) // 64
#define NCH (NB*DH)     // 8192 (b,ch) lanes

typedef __attribute__((ext_vector_type(8))) short bf16x8;
typedef __attribute__((ext_vector_type(4))) float f32x4;

__device__ __forceinline__ unsigned short f2bf(float f) {
  union { float f; unsigned u; } v; v.f = f;
  unsigned r = v.u + 0x7fffu + ((v.u >> 16) & 1u);
  return (unsigned short)(r >> 16);
}

__device__ __forceinline__ float bf2f(unsigned s) {
  union { unsigned u; float f; } v; v.u = s << 16; return v.f;
}

__device__ __forceinline__ unsigned pack_ab(float a, float b) {
  return (unsigned)f2bf(a) | ((unsigned)f2bf(b) << 16);
}

__device__ __forceinline__ float sigmoidf_(float x) {
  return 1.0f / (1.0f + __expf(-x));
}

// ---- cast f32 (strided rows) -> bf16 (packed rows) ----
__global__ void cast_strided_kernel(const float* __restrict__ src,
                                    unsigned short* __restrict__ dst,
                                    int rows, int cols, int src_ld) {
  int cols4 = cols >> 2;
  int total = rows * cols4;
  for (int i = blockIdx.x * blockDim.x + threadIdx.x; i < total;
       i += gridDim.x * blockDim.x) {
    int r  = i / cols4;
    int c4 = i - r * cols4;
    const float4 v = *reinterpret_cast<const float4*>(src + (size_t)r * src_ld + c4 * 4);
    ushort4 o;
    o.x = f2bf(v.x); o.y = f2bf(v.y); o.z = f2bf(v.z); o.w = f2bf(v.w);
    *reinterpret_cast<ushort4*>(dst + (size_t)r * cols + c4 * 4) = o;
  }
}

// ---- hidden-part projections ----
__global__ void hd_kernel(const float* __restrict__ Wg, const float* __restrict__ Wd,
                          const float* __restrict__ hidden,
                          float* __restrict__ hd_gate, float* __restrict__ hd_delta) {
  int wid  = (blockIdx.x * blockDim.x + threadIdx.x) >> 6;
  int lane = threadIdx.x & 63;
  if (wid >= DH + DR) return;
  const float* wrow;
  int ch; bool isGate;
  if (wid < DH) { isGate = true;  ch = wid;      wrow = Wg + (size_t)ch * (DIN + DH) + DIN; }
  else          { isGate = false; ch = wid - DH; wrow = Wd + (size_t)ch * (DIN + DH) + DIN; }
  float acc[NB] = {0.f, 0.f, 0.f, 0.f};
  for (int k = lane; k < DH; k += 64) {
    float w = wrow[k];
    #pragma unroll
    for (int b = 0; b < NB; b++) acc[b] += w * hidden[b * DH + k];
  }
  #pragma unroll
  for (int b = 0; b < NB; b++) {
    float v = acc[b];
    #pragma unroll
    for (int off = 32; off; off >>= 1) v += __shfl_down(v, off);
    if (lane == 0) {
      if (isGate) hd_gate[b * DH + ch] = v;
      else        hd_delta[b * DR + ch] = v;
    }
  }
}

// ---- LDS staging with XOR swizzle: tile [rows][64] bf16 ----
__device__ __forceinline__ void stage_tile(const unsigned short* __restrict__ src,
                                           int src_ld, unsigned short* lds,
                                           int rows, int tid) {
  int nchunks = rows * 8;
  for (int id = tid; id < nchunks; id += 256) {
    int r = id >> 3, c = id & 7;
    uint4 v = *reinterpret_cast<const uint4*>(src + (size_t)r * src_ld + c * 8);
    int csw = c ^ (r & 7);
    *reinterpret_cast<uint4*>(lds + r * 64 + csw * 8) = v;
  }
}

__device__ __forceinline__ bf16x8 read_frag(const unsigned short* lds, int row,
                                            int kk, int lane) {
  int c = (kk * 4 + (lane >> 4)) ^ (row & 7);
  return *reinterpret_cast<const bf16x8*>(lds + row * 64 + c * 8);
}

// ---- GEMM: P = silu(Xb @ Wd_x^T + hd_delta)  -> bf16 [MTOK][DR]
__global__ __launch_bounds__(256, 2) void gemm_P(
    const unsigned short* __restrict__ Xb, const unsigned short* __restrict__ Wdb,
    const float* __restrict__ hd_delta, unsigned short* __restrict__ P) {
  __shared__ __align__(16) unsigned short As[128 * 64];
  __shared__ __align__(16) unsigned short Bs[64 * 64];
  int tid = threadIdx.x, lane = tid & 63, wid = tid >> 6;
  int wm = wid >> 1, wn = wid & 1;
  int bm0 = blockIdx.x * 128;
  int bn0 = blockIdx.y * 64;
  f32x4 acc[4][2];
  #pragma unroll
  for (int m = 0; m < 4; m++)
    #pragma unroll
    for (int n = 0; n < 2; n++) acc[m][n] = (f32x4){0.f, 0.f, 0.f, 0.f};

  for (int k0 = 0; k0 < DIN; k0 += 64) {
    stage_tile(Xb + (size_t)bm0 * DIN + k0, DIN, As, 128, tid);
    stage_tile(Wdb + (size_t)bn0 * DIN + k0, DIN, Bs, 64, tid);
    __syncthreads();
    #pragma unroll
    for (int kk = 0; kk < 2; kk++) {
      bf16x8 af[4], bf[2];
      #pragma unroll
      for (int m = 0; m < 4; m++) af[m] = read_frag(As, wm * 64 + m * 16 + (lane & 15), kk, lane);
      #pragma unroll
      for (int n = 0; n < 2; n++) bf[n] = read_frag(Bs, wn * 32 + n * 16 + (lane & 15), kk, lane);
      #pragma unroll
      for (int m = 0; m < 4; m++)
        #pragma unroll
        for (int n = 0; n < 2; n++)
          acc[m][n] = __builtin_amdgcn_mfma_f32_16x16x32_bf16(af[m], bf[n], acc[m][n], 0, 0, 0);
    }
    __syncthreads();
  }
  int batch = bm0 >> 12;
  #pragma unroll
  for (int n = 0; n < 2; n++) {
    int ch = bn0 + wn * 32 + n * 16 + (lane & 15);
    float hd = hd_delta[batch * DR + ch];
    #pragma unroll
    for (int m = 0; m < 4; m++) {
      #pragma unroll
      for (int r = 0; r < 4; r++) {
        int tok = bm0 + wm * 64 + m * 16 + (lane >> 4) * 4 + r;
        float v = acc[m][n][r] + hd;
        v = v * sigmoidf_(v);   // silu
        P[(size_t)tok * DR + ch] = f2bf(v);
      }
    }
  }
}

// ---- fused GEMM producing packed (a,b) bf16 pairs ----
__global__ __launch_bounds__(256, 2) void gemm_fused(
    const unsigned short* __restrict__ Xb, const unsigned short* __restrict__ Wvb,
    const unsigned short* __restrict__ Wgb, const unsigned short* __restrict__ P,
    const unsigned short* __restrict__ Web,
    const float* __restrict__ b_value, const float* __restrict__ b_gate,
    const float* __restrict__ b_expand, const float* __restrict__ hd_gate,
    unsigned* __restrict__ ws_ab) {
  __shared__ __align__(16) unsigned short As[128 * 64];
  __shared__ __align__(16) unsigned short Bv[64 * 64];
  __shared__ __align__(16) unsigned short Bg[64 * 64];
  int tid = threadIdx.x, lane = tid & 63, wid = tid >> 6;
  int wm = wid >> 1, wn = wid & 1;
  int bm0 = blockIdx.x * 128;
  int bn0 = blockIdx.y * 64;
  f32x4 acc_v[4][2], acc_g[4][2], acc_d[4][2];
  #pragma unroll
  for (int m = 0; m < 4; m++)
    #pragma unroll
    for (int n = 0; n < 2; n++) {
      acc_v[m][n] = (f32x4){0.f, 0.f, 0.f, 0.f};
      acc_g[m][n] = (f32x4){0.f, 0.f, 0.f, 0.f};
      acc_d[m][n] = (f32x4){0.f, 0.f, 0.f, 0.f};
    }

  // K1: value + gate projections (share the X tile)
  for (int k0 = 0; k0 < DIN; k0 += 64) {
    stage_tile(Xb + (size_t)bm0 * DIN + k0, DIN, As, 128, tid);
    stage_tile(Wvb + (size_t)bn0 * DIN + k0, DIN, Bv, 64, tid);
    stage_tile(Wgb + (size_t)bn0 * DIN + k0, DIN, Bg, 64, tid);
    __syncthreads();
    #pragma unroll
    for (int kk = 0; kk < 2; kk++) {
      bf16x8 af[4], bvf[2], bgf[2];
      #pragma unroll
      for (int m = 0; m < 4; m++) af[m] = read_frag(As, wm * 64 + m * 16 + (lane & 15), kk, lane);
      #pragma unroll
      for (int n = 0; n < 2; n++) {
        bvf[n] = read_frag(Bv, wn * 32 + n * 16 + (lane & 15), kk, lane);
        bgf[n] = read_frag(Bg, wn * 32 + n * 16 + (lane & 15), kk, lane);
      }
      #pragma unroll
      for (int m = 0; m < 4; m++)
        #pragma unroll
        for (int n = 0; n < 2; n++) {
          acc_v[m][n] = __builtin_amdgcn_mfma_f32_16x16x32_bf16(af[m], bvf[n], acc_v[m][n], 0, 0, 0);
          acc_g[m][n] = __builtin_amdgcn_mfma_f32_16x16x32_bf16(af[m], bgf[n], acc_g[m][n], 0, 0, 0);
        }
    }
    __syncthreads();
  }
  // K2: delta expand (P @ We^T), K = 256
  for (int k0 = 0; k0 < DR; k0 += 64) {
    stage_tile(P + (size_t)bm0 * DR + k0, DR, As, 128, tid);
    stage_tile(Web + (size_t)bn0 * DR + k0, DR, Bv, 64, tid);
    __syncthreads();
    #pragma unroll
    for (int kk = 0; kk < 2; kk++) {
      bf16x8 af[4], bef[2];
      #pragma unroll
      for (int m = 0; m < 4; m++) af[m] = read_frag(As, wm * 64 + m * 16 + (lane & 15), kk, lane);
      #pragma unroll
      for (int n = 0; n < 2; n++) bef[n] = read_frag(Bv, wn * 32 + n * 16 + (lane & 15), kk, lane);
      #pragma unroll
      for (int m = 0; m < 4; m++)
        #pragma unroll
        for (int n = 0; n < 2; n++)
          acc_d[m][n] = __builtin_amdgcn_mfma_f32_16x16x32_bf16(af[m], bef[n], acc_d[m][n], 0, 0, 0);
    }
    __syncthreads();
  }
  // epilogue: pack a = 1-gate, b = gate*(silu(v)+delta) as 2xbf16
  int batch = bm0 >> 12;
  #pragma unroll
  for (int n = 0; n < 2; n++) {
    int ch = bn0 + wn * 32 + n * 16 + (lane & 15);
    float bv_ = b_value[ch];
    float bg_ = b_gate[ch] + hd_gate[batch * DH + ch];
    float be_ = b_expand[ch];
    #pragma unroll
    for (int m = 0; m < 4; m++) {
      #pragma unroll
      for (int r = 0; r < 4; r++) {
        int tok = bm0 + wm * 64 + m * 16 + (lane >> 4) * 4 + r;
        float vv = acc_v[m][n][r] + bv_;
        vv = vv * sigmoidf_(vv);                       // silu(value)
        float gg = sigmoidf_(acc_g[m][n][r] + bg_);    // gate
        float dd = acc_d[m][n][r] + be_;               // delta
        ws_ab[(size_t)tok * DH + ch] = pack_ab(1.0f - gg, gg * (vv + dd));
      }
    }
  }
}

// ---- scan pass A: per-chunk composition (A = prod a, B = local scan) ----
__global__ __launch_bounds__(256) void scan_partials(const unsigned* __restrict__ ab,
                                                     float2* __restrict__ partial) {
  int id = blockIdx.x * 256 + threadIdx.x;   // 262144
  int q = id & 4095;         // channel-pair index (global)
  int c = id >> 12;          // chunk
  int g = q * 2;             // (b,ch) lane
  int b = g >> 11, ch = g & 2047;
  const unsigned* p = ab + ((size_t)(b * SEQ + c * CL) * DH + ch);
  float A0 = 1.f, B0 = 0.f, A1 = 1.f, B1 = 0.f;
  #pragma unroll 8
  for (int i = 0; i < CL; i++) {
    uint2 u = *reinterpret_cast<const uint2*>(p + (size_t)i * DH);
    float a0 = bf2f(u.x & 0xffffu), b0 = bf2f(u.x >> 16);
    float a1 = bf2f(u.y & 0xffffu), b1 = bf2f(u.y >> 16);
    B0 = fmaf(a0, B0, b0); A0 *= a0;
    B1 = fmaf(a1, B1, b1); A1 *= a1;
  }
  float4 w = {A0, B0, A1, B1};
  *reinterpret_cast<float4*>(partial + (size_t)c * NCH + g) = w;
}

// ---- scan pass B: sequential scan over chunk aggregates, emit prefixes + h_last ----
__global__ void scan_chunks(const float2* __restrict__ partial,
                            const float* __restrict__ hidden,
                            float* __restrict__ prefix, float* __restrict__ out) {
  int g = blockIdx.x * 256 + threadIdx.x;    // 8192
  float H = hidden[g];
  for (int c = 0; c < NCHUNK; c++) {
    prefix[c * NCH + g] = H;
    float2 AB = partial[(size_t)c * NCH + g];
    H = fmaf(AB.x, H, AB.y);
  }
  out[(size_t)MTOK * DH + g] = H;            // h_last
}

// ---- scan pass C: apply prefix, write h_all ----
__global__ __launch_bounds__(256) void scan_apply(const unsigned* __restrict__ ab,
                                                  const float* __restrict__ prefix,
                                                  float* __restrict__ out) {
  int id = blockIdx.x * 256 + threadIdx.x;   // 262144
  int q = id & 4095;
  int c = id >> 12;
  int g = q * 2;
  int b = g >> 11, ch = g & 2047;
  size_t base = (size_t)(b * SEQ + c * CL) * DH + ch;
  const unsigned* p = ab + base;
  float* o = out + base;
  float h0 = prefix[c * NCH + g];
  float h1 = prefix[c * NCH + g + 1];
  #pragma unroll 8
  for (int i = 0; i < CL; i++) {
    uint2 u = *reinterpret_cast<const uint2*>(p + (size_t)i * DH);
    float a0 = bf2f(u.x & 0xffffu), b0 = bf2f(u.x >> 16);
    float a1 = bf2f(u.y & 0xffffu), b1 = bf2f(u.y >> 16);
    h0 = fmaf(a0, h0, b0);
    h1 = fmaf(a1, h1, b1);
    float2 w = {h0, h1};
    *reinterpret_cast<float2*>(o + (size_t)i * DH) = w;
  }
}

extern "C" void kernel_launch(void* const* d_in, const int* in_sizes, int n_in,
                              void* d_out, int out_size, void* d_ws, size_t ws_size,
                              hipStream_t stream) {
  (void)in_sizes; (void)n_in; (void)out_size; (void)ws_size;
  const float* x      = (const float*)d_in[0];
  const float* hidden = (const float*)d_in[1];
  const float* Wd     = (const float*)d_in[2];
  const float* We     = (const float*)d_in[3];
  const float* be     = (const float*)d_in[4];
  const float* Wg     = (const float*)d_in[5];
  const float* bg     = (const float*)d_in[6];
  const float* Wv     = (const float*)d_in[7];
  const float* bv     = (const float*)d_in[8];
  float* out = (float*)d_out;
  char* ws = (char*)d_ws;

  // ws_ab is MTOK*DH uint32 = 134217728 B (NOT 67 MB — R2's bug).
  unsigned*       ws_ab    = (unsigned*)(ws);                    // [0, 134217728)
  unsigned short* Xb       = (unsigned short*)(ws + 134217728);  // 33554432 B
  unsigned short* Pb       = (unsigned short*)(ws + 167772160);  // 8388608 B
  unsigned short* Wvb      = (unsigned short*)(ws + 176160768);  // 4194304 B
  unsigned short* Wgb      = (unsigned short*)(ws + 180355072);  // 4194304 B
  unsigned short* Wdb      = (unsigned short*)(ws + 184549376);  // 524288 B
  unsigned short* Web      = (unsigned short*)(ws + 185073664);  // 1048576 B
  float*          hd_gate  = (float*)(ws + 186122240);           // 32768 B
  float*          hd_delta = (float*)(ws + 186155008);           // 4096 B
  // partial/prefix alias the Xb region — Xb is dead once gemm_fused completes,
  // and scan_partials launches strictly after it on the same stream.
  float2*         partial  = (float2*)(ws + 134217728);          // 4194304 B
  float*          prefix   = (float*)(ws + 138412032);           // 2097152 B

  // bf16 casts
  cast_strided_kernel<<<2048, 256, 0, stream>>>(x,  Xb,  MTOK, DIN, DIN);
  cast_strided_kernel<<<512,  256, 0, stream>>>(Wv, Wvb, DH,   DIN, DIN);
  cast_strided_kernel<<<512,  256, 0, stream>>>(Wg, Wgb, DH,   DIN, DIN + DH);
  cast_strided_kernel<<<64,   256, 0, stream>>>(Wd, Wdb, DR,   DIN, DIN + DH);
  cast_strided_kernel<<<128,  256, 0, stream>>>(We, Web, DH,   DR,  DR);
  // hidden-part bias projections
  hd_kernel<<<(DH + DR) / 4, 256, 0, stream>>>(Wg, Wd, hidden, hd_gate, hd_delta);
  // P = silu(delta_latent)
  gemm_P<<<dim3(MTOK / 128, DR / 64), 256, 0, stream>>>(Xb, Wdb, hd_delta, Pb);
  // packed (a,b)
  gemm_fused<<<dim3(MTOK / 128, DH / 64), 256, 0, stream>>>(
      Xb, Wvb, Wgb, Pb, Web, bv, bg, be, hd_gate, ws_ab);
  // hierarchical linear-recurrence scan
  scan_partials<<<(NCH/2) * NCHUNK / 256, 256, 0, stream>>>(ws_ab, partial);
  scan_chunks<<<NCH / 256, 256, 0, stream>>>(partial, hidden, prefix, out);
  scan_apply<<<(NCH/2) * NCHUNK / 256, 256, 0, stream>>>(ws_ab, prefix, out);
}

// Round 6
// 339.258 us; speedup vs baseline: 2.7933x; 1.5593x over previous
//
#include <hip/hip_runtime.h>
#include <hip/hip_bf16.h>
#include <cstdint>

#define DIN 1024
#define DH  2048
#define DR  256
#define SEQ 4096
#define NB  4
#define MTOK (NB*SEQ)   // 16384
#define NCHUNK 64
#define CL (SEQ/NCHUNK) // 64
#define NCH (NB*DH)     // 8192 (b,ch) lanes

typedef __attribute__((ext_vector_type(8))) short bf16x8;
typedef __attribute__((ext_vector_type(4))) float f32x4;

__device__ __forceinline__ unsigned short f2bf(float f) {
  union { float f; unsigned u; } v; v.f = f;
  unsigned r = v.u + 0x7fffu + ((v.u >> 16) & 1u);
  return (unsigned short)(r >> 16);
}

__device__ __forceinline__ float bf2f(unsigned s) {
  union { unsigned u; float f; } v; v.u = s << 16; return v.f;
}

__device__ __forceinline__ unsigned pack_ab(float a, float b) {
  return (unsigned)f2bf(a) | ((unsigned)f2bf(b) << 16);
}

__device__ __forceinline__ float sigmoidf_(float x) {
  return 1.0f / (1.0f + __expf(-x));
}

// ---- cast f32 (strided rows) -> bf16 (packed rows) ----
__global__ void cast_strided_kernel(const float* __restrict__ src,
                                    unsigned short* __restrict__ dst,
                                    int rows, int cols, int src_ld) {
  int cols4 = cols >> 2;
  int total = rows * cols4;
  for (int i = blockIdx.x * blockDim.x + threadIdx.x; i < total;
       i += gridDim.x * blockDim.x) {
    int r  = i / cols4;
    int c4 = i - r * cols4;
    const float4 v = *reinterpret_cast<const float4*>(src + (size_t)r * src_ld + c4 * 4);
    ushort4 o;
    o.x = f2bf(v.x); o.y = f2bf(v.y); o.z = f2bf(v.z); o.w = f2bf(v.w);
    *reinterpret_cast<ushort4*>(dst + (size_t)r * cols + c4 * 4) = o;
  }
}

// ---- hidden-part projections ----
__global__ void hd_kernel(const float* __restrict__ Wg, const float* __restrict__ Wd,
                          const float* __restrict__ hidden,
                          float* __restrict__ hd_gate, float* __restrict__ hd_delta) {
  int wid  = (blockIdx.x * blockDim.x + threadIdx.x) >> 6;
  int lane = threadIdx.x & 63;
  if (wid >= DH + DR) return;
  const float* wrow;
  int ch; bool isGate;
  if (wid < DH) { isGate = true;  ch = wid;      wrow = Wg + (size_t)ch * (DIN + DH) + DIN; }
  else          { isGate = false; ch = wid - DH; wrow = Wd + (size_t)ch * (DIN + DH) + DIN; }
  float acc[NB] = {0.f, 0.f, 0.f, 0.f};
  for (int k = lane; k < DH; k += 64) {
    float w = wrow[k];
    #pragma unroll
    for (int b = 0; b < NB; b++) acc[b] += w * hidden[b * DH + k];
  }
  #pragma unroll
  for (int b = 0; b < NB; b++) {
    float v = acc[b];
    #pragma unroll
    for (int off = 32; off; off >>= 1) v += __shfl_down(v, off);
    if (lane == 0) {
      if (isGate) hd_gate[b * DH + ch] = v;
      else        hd_delta[b * DR + ch] = v;
    }
  }
}

// ---- async LDS staging via global_load_lds (rule #21: linear LDS dest,
//      pre-swizzled SOURCE, swizzled read). Tile = [rows][64] bf16.
//      One wave-issue covers 8 rows (64 lanes x 16B = 1024B segment).
//      Lane l: row r = seg*8 + (l>>3), LDS slot s = l&7, source chunk
//      c = (l&7) ^ ((l>>3)&7)  (== s ^ (r&7) since seg*8 % 8 == 0),
//      so LDS slot s ends up holding chunk s ^ (r&7) — matching read_frag.
__device__ __forceinline__ void stage_async(const unsigned short* __restrict__ src,
                                            int src_ld, unsigned short* lds,
                                            int rows, int wid, int lane) {
  int r8 = lane >> 3;
  int c  = (lane & 7) ^ (r8 & 7);
  const unsigned short* g0 = src + (size_t)r8 * src_ld + c * 8;
  int nsegs = rows >> 3;
  for (int s = wid; s < nsegs; s += 4) {
    const unsigned short* g = g0 + (size_t)(s * 8) * src_ld;
    __builtin_amdgcn_global_load_lds(
        (const __attribute__((address_space(1))) void*)g,
        (__attribute__((address_space(3))) void*)(lds + s * 512),
        16, 0, 0);
  }
}

__device__ __forceinline__ bf16x8 read_frag(const unsigned short* lds, int row,
                                            int kk, int lane) {
  int c = (kk * 4 + (lane >> 4)) ^ (row & 7);
  return *reinterpret_cast<const bf16x8*>(lds + row * 64 + c * 8);
}

// ---- GEMM: P = silu(Xb @ Wd_x^T + hd_delta)  -> bf16 [MTOK][DR]
__global__ __launch_bounds__(256, 2) void gemm_P(
    const unsigned short* __restrict__ Xb, const unsigned short* __restrict__ Wdb,
    const float* __restrict__ hd_delta, unsigned short* __restrict__ P) {
  __shared__ __align__(16) unsigned short As[128 * 64];
  __shared__ __align__(16) unsigned short Bs[64 * 64];
  int tid = threadIdx.x, lane = tid & 63, wid = tid >> 6;
  int wm = wid >> 1, wn = wid & 1;
  int bm0 = blockIdx.x * 128;
  int bn0 = blockIdx.y * 64;
  f32x4 acc[4][2];
  #pragma unroll
  for (int m = 0; m < 4; m++)
    #pragma unroll
    for (int n = 0; n < 2; n++) acc[m][n] = (f32x4){0.f, 0.f, 0.f, 0.f};

  for (int k0 = 0; k0 < DIN; k0 += 64) {
    stage_async(Xb + (size_t)bm0 * DIN + k0, DIN, As, 128, wid, lane);
    stage_async(Wdb + (size_t)bn0 * DIN + k0, DIN, Bs, 64, wid, lane);
    __syncthreads();
    #pragma unroll
    for (int kk = 0; kk < 2; kk++) {
      bf16x8 af[4], bf[2];
      #pragma unroll
      for (int m = 0; m < 4; m++) af[m] = read_frag(As, wm * 64 + m * 16 + (lane & 15), kk, lane);
      #pragma unroll
      for (int n = 0; n < 2; n++) bf[n] = read_frag(Bs, wn * 32 + n * 16 + (lane & 15), kk, lane);
      #pragma unroll
      for (int m = 0; m < 4; m++)
        #pragma unroll
        for (int n = 0; n < 2; n++)
          acc[m][n] = __builtin_amdgcn_mfma_f32_16x16x32_bf16(af[m], bf[n], acc[m][n], 0, 0, 0);
    }
    __syncthreads();
  }
  int batch = bm0 >> 12;
  #pragma unroll
  for (int n = 0; n < 2; n++) {
    int ch = bn0 + wn * 32 + n * 16 + (lane & 15);
    float hd = hd_delta[batch * DR + ch];
    #pragma unroll
    for (int m = 0; m < 4; m++) {
      #pragma unroll
      for (int r = 0; r < 4; r++) {
        int tok = bm0 + wm * 64 + m * 16 + (lane >> 4) * 4 + r;
        float v = acc[m][n][r] + hd;
        v = v * sigmoidf_(v);   // silu
        P[(size_t)tok * DR + ch] = f2bf(v);
      }
    }
  }
}

// ---- fused GEMM producing packed (a,b) bf16 pairs ----
__global__ __launch_bounds__(256, 2) void gemm_fused(
    const unsigned short* __restrict__ Xb, const unsigned short* __restrict__ Wvb,
    const unsigned short* __restrict__ Wgb, const unsigned short* __restrict__ P,
    const unsigned short* __restrict__ Web,
    const float* __restrict__ b_value, const float* __restrict__ b_gate,
    const float* __restrict__ b_expand, const float* __restrict__ hd_gate,
    unsigned* __restrict__ ws_ab) {
  __shared__ __align__(16) unsigned short As[128 * 64];
  __shared__ __align__(16) unsigned short Bv[64 * 64];
  __shared__ __align__(16) unsigned short Bg[64 * 64];
  int tid = threadIdx.x, lane = tid & 63, wid = tid >> 6;
  int wm = wid >> 1, wn = wid & 1;
  int bm0 = blockIdx.x * 128;
  int bn0 = blockIdx.y * 64;
  f32x4 acc_v[4][2], acc_g[4][2], acc_d[4][2];
  #pragma unroll
  for (int m = 0; m < 4; m++)
    #pragma unroll
    for (int n = 0; n < 2; n++) {
      acc_v[m][n] = (f32x4){0.f, 0.f, 0.f, 0.f};
      acc_g[m][n] = (f32x4){0.f, 0.f, 0.f, 0.f};
      acc_d[m][n] = (f32x4){0.f, 0.f, 0.f, 0.f};
    }

  // K1: value + gate projections (share the X tile)
  for (int k0 = 0; k0 < DIN; k0 += 64) {
    stage_async(Xb + (size_t)bm0 * DIN + k0, DIN, As, 128, wid, lane);
    stage_async(Wvb + (size_t)bn0 * DIN + k0, DIN, Bv, 64, wid, lane);
    stage_async(Wgb + (size_t)bn0 * DIN + k0, DIN, Bg, 64, wid, lane);
    __syncthreads();
    #pragma unroll
    for (int kk = 0; kk < 2; kk++) {
      bf16x8 af[4], bvf[2], bgf[2];
      #pragma unroll
      for (int m = 0; m < 4; m++) af[m] = read_frag(As, wm * 64 + m * 16 + (lane & 15), kk, lane);
      #pragma unroll
      for (int n = 0; n < 2; n++) {
        bvf[n] = read_frag(Bv, wn * 32 + n * 16 + (lane & 15), kk, lane);
        bgf[n] = read_frag(Bg, wn * 32 + n * 16 + (lane & 15), kk, lane);
      }
      #pragma unroll
      for (int m = 0; m < 4; m++)
        #pragma unroll
        for (int n = 0; n < 2; n++) {
          acc_v[m][n] = __builtin_amdgcn_mfma_f32_16x16x32_bf16(af[m], bvf[n], acc_v[m][n], 0, 0, 0);
          acc_g[m][n] = __builtin_amdgcn_mfma_f32_16x16x32_bf16(af[m], bgf[n], acc_g[m][n], 0, 0, 0);
        }
    }
    __syncthreads();
  }
  // K2: delta expand (P @ We^T), K = 256
  for (int k0 = 0; k0 < DR; k0 += 64) {
    stage_async(P + (size_t)bm0 * DR + k0, DR, As, 128, wid, lane);
    stage_async(Web + (size_t)bn0 * DR + k0, DR, Bv, 64, wid, lane);
    __syncthreads();
    #pragma unroll
    for (int kk = 0; kk < 2; kk++) {
      bf16x8 af[4], bef[2];
      #pragma unroll
      for (int m = 0; m < 4; m++) af[m] = read_frag(As, wm * 64 + m * 16 + (lane & 15), kk, lane);
      #pragma unroll
      for (int n = 0; n < 2; n++) bef[n] = read_frag(Bv, wn * 32 + n * 16 + (lane & 15), kk, lane);
      #pragma unroll
      for (int m = 0; m < 4; m++)
        #pragma unroll
        for (int n = 0; n < 2; n++)
          acc_d[m][n] = __builtin_amdgcn_mfma_f32_16x16x32_bf16(af[m], bef[n], acc_d[m][n], 0, 0, 0);
    }
    __syncthreads();
  }
  // epilogue: pack a = 1-gate, b = gate*(silu(v)+delta) as 2xbf16
  int batch = bm0 >> 12;
  #pragma unroll
  for (int n = 0; n < 2; n++) {
    int ch = bn0 + wn * 32 + n * 16 + (lane & 15);
    float bv_ = b_value[ch];
    float bg_ = b_gate[ch] + hd_gate[batch * DH + ch];
    float be_ = b_expand[ch];
    #pragma unroll
    for (int m = 0; m < 4; m++) {
      #pragma unroll
      for (int r = 0; r < 4; r++) {
        int tok = bm0 + wm * 64 + m * 16 + (lane >> 4) * 4 + r;
        float vv = acc_v[m][n][r] + bv_;
        vv = vv * sigmoidf_(vv);                       // silu(value)
        float gg = sigmoidf_(acc_g[m][n][r] + bg_);    // gate
        float dd = acc_d[m][n][r] + be_;               // delta
        ws_ab[(size_t)tok * DH + ch] = pack_ab(1.0f - gg, gg * (vv + dd));
      }
    }
  }
}

// ---- scan pass A: per-chunk composition (A = prod a, B = local scan) ----
__global__ __launch_bounds__(256) void scan_partials(const unsigned* __restrict__ ab,
                                                     float2* __restrict__ partial) {
  int id = blockIdx.x * 256 + threadIdx.x;   // 262144
  int q = id & 4095;         // channel-pair index (global)
  int c = id >> 12;          // chunk
  int g = q * 2;             // (b,ch) lane
  int b = g >> 11, ch = g & 2047;
  const unsigned* p = ab + ((size_t)(b * SEQ + c * CL) * DH + ch);
  float A0 = 1.f, B0 = 0.f, A1 = 1.f, B1 = 0.f;
  #pragma unroll 8
  for (int i = 0; i < CL; i++) {
    uint2 u = *reinterpret_cast<const uint2*>(p + (size_t)i * DH);
    float a0 = bf2f(u.x & 0xffffu), b0 = bf2f(u.x >> 16);
    float a1 = bf2f(u.y & 0xffffu), b1 = bf2f(u.y >> 16);
    B0 = fmaf(a0, B0, b0); A0 *= a0;
    B1 = fmaf(a1, B1, b1); A1 *= a1;
  }
  float4 w = {A0, B0, A1, B1};
  *reinterpret_cast<float4*>(partial + (size_t)c * NCH + g) = w;
}

// ---- scan pass B: sequential scan over chunk aggregates, emit prefixes + h_last ----
__global__ void scan_chunks(const float2* __restrict__ partial,
                            const float* __restrict__ hidden,
                            float* __restrict__ prefix, float* __restrict__ out) {
  int g = blockIdx.x * 256 + threadIdx.x;    // 8192
  float H = hidden[g];
  for (int c = 0; c < NCHUNK; c++) {
    prefix[c * NCH + g] = H;
    float2 AB = partial[(size_t)c * NCH + g];
    H = fmaf(AB.x, H, AB.y);
  }
  out[(size_t)MTOK * DH + g] = H;            // h_last
}

// ---- scan pass C: apply prefix, write h_all ----
__global__ __launch_bounds__(256) void scan_apply(const unsigned* __restrict__ ab,
                                                  const float* __restrict__ prefix,
                                                  float* __restrict__ out) {
  int id = blockIdx.x * 256 + threadIdx.x;   // 262144
  int q = id & 4095;
  int c = id >> 12;
  int g = q * 2;
  int b = g >> 11, ch = g & 2047;
  size_t base = (size_t)(b * SEQ + c * CL) * DH + ch;
  const unsigned* p = ab + base;
  float* o = out + base;
  float h0 = prefix[c * NCH + g];
  float h1 = prefix[c * NCH + g + 1];
  #pragma unroll 8
  for (int i = 0; i < CL; i++) {
    uint2 u = *reinterpret_cast<const uint2*>(p + (size_t)i * DH);
    float a0 = bf2f(u.x & 0xffffu), b0 = bf2f(u.x >> 16);
    float a1 = bf2f(u.y & 0xffffu), b1 = bf2f(u.y >> 16);
    h0 = fmaf(a0, h0, b0);
    h1 = fmaf(a1, h1, b1);
    float2 w = {h0, h1};
    *reinterpret_cast<float2*>(o + (size_t)i * DH) = w;
  }
}

extern "C" void kernel_launch(void* const* d_in, const int* in_sizes, int n_in,
                              void* d_out, int out_size, void* d_ws, size_t ws_size,
                              hipStream_t stream) {
  (void)in_sizes; (void)n_in; (void)out_size; (void)ws_size;
  const float* x      = (const float*)d_in[0];
  const float* hidden = (const float*)d_in[1];
  const float* Wd     = (const float*)d_in[2];
  const float* We     = (const float*)d_in[3];
  const float* be     = (const float*)d_in[4];
  const float* Wg     = (const float*)d_in[5];
  const float* bg     = (const float*)d_in[6];
  const float* Wv     = (const float*)d_in[7];
  const float* bv     = (const float*)d_in[8];
  float* out = (float*)d_out;
  char* ws = (char*)d_ws;

  // ws_ab is MTOK*DH uint32 = 134217728 B.
  unsigned*       ws_ab    = (unsigned*)(ws);                    // [0, 134217728)
  unsigned short* Xb       = (unsigned short*)(ws + 134217728);  // 33554432 B
  unsigned short* Pb       = (unsigned short*)(ws + 167772160);  // 8388608 B
  unsigned short* Wvb      = (unsigned short*)(ws + 176160768);  // 4194304 B
  unsigned short* Wgb      = (unsigned short*)(ws + 180355072);  // 4194304 B
  unsigned short* Wdb      = (unsigned short*)(ws + 184549376);  // 524288 B
  unsigned short* Web      = (unsigned short*)(ws + 185073664);  // 1048576 B
  float*          hd_gate  = (float*)(ws + 186122240);           // 32768 B
  float*          hd_delta = (float*)(ws + 186155008);           // 4096 B
  // partial/prefix alias the Xb region — Xb is dead once gemm_fused completes,
  // and scan_partials launches strictly after it on the same stream.
  float2*         partial  = (float2*)(ws + 134217728);          // 4194304 B
  float*          prefix   = (float*)(ws + 138412032);           // 2097152 B

  // bf16 casts
  cast_strided_kernel<<<2048, 256, 0, stream>>>(x,  Xb,  MTOK, DIN, DIN);
  cast_strided_kernel<<<512,  256, 0, stream>>>(Wv, Wvb, DH,   DIN, DIN);
  cast_strided_kernel<<<512,  256, 0, stream>>>(Wg, Wgb, DH,   DIN, DIN + DH);
  cast_strided_kernel<<<64,   256, 0, stream>>>(Wd, Wdb, DR,   DIN, DIN + DH);
  cast_strided_kernel<<<128,  256, 0, stream>>>(We, Web, DH,   DR,  DR);
  // hidden-part bias projections
  hd_kernel<<<(DH + DR) / 4, 256, 0, stream>>>(Wg, Wd, hidden, hd_gate, hd_delta);
  // P = silu(delta_latent)
  gemm_P<<<dim3(MTOK / 128, DR / 64), 256, 0, stream>>>(Xb, Wdb, hd_delta, Pb);
  // packed (a,b)
  gemm_fused<<<dim3(MTOK / 128, DH / 64), 256, 0, stream>>>(
      Xb, Wvb, Wgb, Pb, Web, bv, bg, be, hd_gate, ws_ab);
  // hierarchical linear-recurrence scan
  scan_partials<<<(NCH/2) * NCHUNK / 256, 256, 0, stream>>>(ws_ab, partial);
  scan_chunks<<<NCH / 256, 256, 0, stream>>>(partial, hidden, prefix, out);
  scan_apply<<<(NCH/2) * NCHUNK / 256, 256, 0, stream>>>(ws_ab, prefix, out);
}